// Round 18
// baseline (194.589 us; speedup 1.0000x reference)
//
#include <hip/hip_runtime.h>

typedef __attribute__((ext_vector_type(8))) __bf16 bf16x8;
typedef __attribute__((ext_vector_type(4))) __bf16 bf16x4;
typedef __attribute__((ext_vector_type(4))) float f32x4;
typedef __attribute__((ext_vector_type(4))) unsigned int u32x4;
typedef __attribute__((ext_vector_type(4))) unsigned short u16x4;
typedef __attribute__((ext_vector_type(8))) unsigned short u16x8;
typedef __attribute__((ext_vector_type(4))) short s16x4;
typedef unsigned short u16;

static __device__ __forceinline__ u16 f2b(float f) {
    unsigned u = __builtin_bit_cast(unsigned, f);
    u = (u + 0x7FFFu + ((u >> 16) & 1u)) >> 16;
    return (u16)u;
}
static __device__ __forceinline__ float b2f(u16 u) {
    return __builtin_bit_cast(float, ((unsigned)u) << 16);
}
static __device__ __forceinline__ float fexp2(float x) {
#if __has_builtin(__builtin_amdgcn_exp2f)
    return __builtin_amdgcn_exp2f(x);
#else
    return exp2f(x);
#endif
}
static __device__ __forceinline__ f32x4 mfma16(bf16x4 a, bf16x4 b, f32x4 c) {
#if __has_builtin(__builtin_amdgcn_mfma_f32_16x16x16_bf16)
    return __builtin_amdgcn_mfma_f32_16x16x16_bf16(a, b, c, 0, 0, 0);
#else
    return __builtin_amdgcn_mfma_f32_16x16x16bf16_1k(
        __builtin_bit_cast(s16x4, a), __builtin_bit_cast(s16x4, b), c, 0, 0, 0);
#endif
}

// async global->LDS, 16B per lane; LDS dest = wave-uniform base + lane*16
static __device__ __forceinline__ void gload16(const u16* g, u16* l) {
    __builtin_amdgcn_global_load_lds(
        (const __attribute__((address_space(1))) unsigned int*)g,
        (__attribute__((address_space(3))) unsigned int*)l, 16, 0, 0);
}

// ---------------- weight transpose+convert: src[K][N] f32 -> dst[N][K] bf16 ----
__global__ __launch_bounds__(256) void prep_w(
    const float* __restrict__ Wq, const float* __restrict__ Wk,
    const float* __restrict__ Wv, const float* __restrict__ Wo,
    const float* __restrict__ W1, const float* __restrict__ W2,
    u16* __restrict__ WqkvT, u16* __restrict__ WoT,
    u16* __restrict__ W1T, u16* __restrict__ W2T)
{
    const int i = blockIdx.x;
    const float* src; u16* dst; int K, N, nt, kt;
    if (i < 1024) {
        const int z = i >> 8, idx = i & 255;
        K = 512; N = 512; nt = (idx & 15) * 32; kt = (idx >> 4) * 32;
        if (z == 0)      { src = Wq; dst = WqkvT; }
        else if (z == 1) { src = Wk; dst = WqkvT + 512*512; }
        else if (z == 2) { src = Wv; dst = WqkvT + 1024*512; }
        else             { src = Wo; dst = WoT; }
    } else if (i < 2048) {
        const int idx = i - 1024;
        src = W1; dst = W1T; K = 512; N = 2048;
        nt = (idx & 63) * 32; kt = (idx >> 6) * 32;
    } else {
        const int idx = i - 2048;
        src = W2; dst = W2T; K = 2048; N = 512;
        nt = (idx & 15) * 32; kt = (idx >> 4) * 32;
    }
    __shared__ float tile[32][33];
    const int tx = threadIdx.x & 31, ty = threadIdx.x >> 5;
    #pragma unroll
    for (int r = 0; r < 4; ++r)
        tile[ty + r*8][tx] = src[(size_t)(kt + ty + r*8) * N + nt + tx];
    __syncthreads();
    #pragma unroll
    for (int r = 0; r < 4; ++r)
        dst[(size_t)(nt + ty + r*8) * K + kt + tx] = f2b(tile[tx][ty + r*8]);
}

// ---------------- LayerNorm rows: [8192][512] f32 -> bf16 ----------------------
__global__ __launch_bounds__(256) void ln_rows(
    const float* __restrict__ x, const float* __restrict__ g,
    const float* __restrict__ b, u16* __restrict__ out)
{
    const int row = blockIdx.x * 4 + (threadIdx.x >> 6);
    const int lane = threadIdx.x & 63;
    const float* xr = x + (size_t)row * 512;
    f32x4 v0 = *(const f32x4*)(xr + lane * 4);
    f32x4 v1 = *(const f32x4*)(xr + 256 + lane * 4);
    float s = v0[0]+v0[1]+v0[2]+v0[3]+v1[0]+v1[1]+v1[2]+v1[3];
    #pragma unroll
    for (int o = 1; o < 64; o <<= 1) s += __shfl_xor(s, o);
    const float mu = s * (1.0f / 512.0f);
    float s2 = 0.f;
    #pragma unroll
    for (int i = 0; i < 4; ++i) { float d0 = v0[i]-mu, d1 = v1[i]-mu; s2 += d0*d0 + d1*d1; }
    #pragma unroll
    for (int o = 1; o < 64; o <<= 1) s2 += __shfl_xor(s2, o);
    const float inv = rsqrtf(s2 * (1.0f/512.0f) + 1e-5f);
    f32x4 g0 = *(const f32x4*)(g + lane*4), g1 = *(const f32x4*)(g + 256 + lane*4);
    f32x4 b0 = *(const f32x4*)(b + lane*4), b1 = *(const f32x4*)(b + 256 + lane*4);
    u16x4 p0, p1;
    #pragma unroll
    for (int i = 0; i < 4; ++i) {
        p0[i] = f2b((v0[i]-mu)*inv*g0[i] + b0[i]);
        p1[i] = f2b((v1[i]-mu)*inv*g1[i] + b1[i]);
    }
    u16* orow = out + (size_t)row * 512;
    *(u16x4*)(orow + lane*4)       = p0;
    *(u16x4*)(orow + 256 + lane*4) = p1;
}

// ---------------- GEMM 128xN tile (QKV / FFN1) ---------------------------------
// FLAGS: 1=bias, 2=residual(f32), 4=relu, 8=store f32 (else bf16),
//        16=scale cols<512 by 512^-0.5*log2(e), 32=cols>=1024 -> write V^T to vt
// GX = grid cols. 1D grid, XCD-aware: xcd=fid&7, s=fid>>3, col=s%GX, row=xcd*8+s/GX.
// NB=2: 3-slot ring, vmcnt(4). Counted vmcnt + raw s_barrier; stage AFTER barrier.
template<int FLAGS, int NB, int GX>
__global__ __launch_bounds__(256) void gemm_bt(
    const u16* __restrict__ A, const u16* __restrict__ BT,
    const int N, const int K,
    const float* __restrict__ bias, const float* __restrict__ res,
    void* __restrict__ outv, u16* __restrict__ vt)
{
    constexpr int RING = (NB == 2) ? 3 : 4;
    __shared__ __attribute__((aligned(16))) u16 As[RING * 4096];
    __shared__ __attribute__((aligned(16))) u16 Bs[RING * 2048 * NB];
    const int fid = blockIdx.x;
    const int xcd = fid & 7, s8 = fid >> 3;
    const int colb = s8 % GX, rl = s8 / GX;
    const int m0 = (xcd*8 + rl) << 7;
    const int n0 = colb * (64 * NB);
    const int tid = threadIdx.x, lane = tid & 63, w = tid >> 6;
    const int wr2 = w >> 1, wc = w & 1;
    const int g = lane >> 4, c = lane & 15;
    const f32x4 fz = {0.f, 0.f, 0.f, 0.f};

    f32x4 acc[4][2 * NB];
    #pragma unroll
    for (int m = 0; m < 4; ++m)
      #pragma unroll
      for (int n = 0; n < 2 * NB; ++n) acc[m][n] = fz;

    const int srow = tid >> 2;
    const int scs = (((tid & 3) ^ (srow & 3)) * 8);
    const u16* Ag = A  + (size_t)(m0 + srow)*K + scs;
    const u16* Bg = BT + (size_t)(n0 + srow)*K + scs;
    const size_t rstep = (size_t)64 * K;

    const int nkt = K >> 5;
    auto stage = [&](int slot, int kt) {
        const int k0 = kt << 5;
        u16* ad = &As[0] + slot*4096 + w*512;
        gload16(Ag + k0,         ad);
        gload16(Ag + rstep + k0, ad + 2048);
        u16* bd = &Bs[0] + slot*2048*NB + w*512;
        gload16(Bg + k0, bd);
        if constexpr (NB == 2) gload16(Bg + rstep + k0, bd + 2048);
    };
    stage(0, 0);
    stage(1, (1 < nkt) ? 1 : 0);
    if constexpr (RING == 4) stage(2, (2 < nkt) ? 2 : 0);

    for (int kt = 0; kt < nkt; ++kt) {
        if constexpr (NB == 2) asm volatile("s_waitcnt vmcnt(4)" ::: "memory");
        else                   asm volatile("s_waitcnt vmcnt(6)" ::: "memory");
        __builtin_amdgcn_s_barrier();
        asm volatile("" ::: "memory");
        {
            int tp = kt + RING - 1; if (tp >= nkt) tp = nkt - 1;
            int sl = kt + RING - 1; sl -= (sl / RING) * RING;
            stage(sl, tp);
        }
        const int rd = kt - (kt / RING) * RING;
        const u16* Ab = &As[0] + rd*4096;
        const u16* Bb = &Bs[0] + rd*2048*NB;
        bf16x8 af[4], bfr[2 * NB];
        #pragma unroll
        for (int m = 0; m < 4; ++m) {
            const int row = wr2*64 + m*16 + c;
            af[m] = *(const bf16x8*)(Ab + row*32 + (((g*16) ^ ((row&3)<<4)) >> 1));
        }
        #pragma unroll
        for (int n = 0; n < 2 * NB; ++n) {
            const int row = wc*(32*NB) + n*16 + c;
            bfr[n] = *(const bf16x8*)(Bb + row*32 + (((g*16) ^ ((row&3)<<4)) >> 1));
        }
        #pragma unroll
        for (int m = 0; m < 4; ++m)
          #pragma unroll
          for (int n = 0; n < 2 * NB; ++n)
            acc[m][n] = __builtin_amdgcn_mfma_f32_16x16x32_bf16(af[m], bfr[n], acc[m][n], 0, 0, 0);
    }

    #pragma unroll
    for (int m = 0; m < 4; ++m) {
        const int row = m0 + wr2*64 + m*16 + 4*g;
        #pragma unroll
        for (int n = 0; n < 2 * NB; ++n) {
            const int col = n0 + wc*(32*NB) + n*16 + c;
            const float bv = (FLAGS & 1) ? bias[col] : 0.0f;
            float vv[4];
            #pragma unroll
            for (int r = 0; r < 4; ++r) {
                float v = acc[m][n][r] + bv;
                if (FLAGS & 16) v *= (col < 512) ? 0.0637587246f : 1.0f;
                if (FLAGS & 2) v += res[(size_t)(row + r)*N + col];
                if (FLAGS & 4) v = fmaxf(v, 0.0f);
                vv[r] = v;
            }
            if ((FLAGS & 32) && col >= 1024) {
                u16x4 pv;
                #pragma unroll
                for (int r = 0; r < 4; ++r) pv[r] = f2b(vv[r]);
                *(u16x4*)(vt + (size_t)((row >> 12)*512 + (col - 1024))*4096
                             + (row & 4095)) = pv;
            } else if (FLAGS & 8) {
                #pragma unroll
                for (int r = 0; r < 4; ++r)
                    ((float*)outv)[(size_t)(row + r)*N + col] = vv[r];
            } else {
                #pragma unroll
                for (int r = 0; r < 4; ++r)
                    ((u16*)outv)[(size_t)(row + r)*N + col] = f2b(vv[r]);
            }
        }
    }
}

// ---------------- GEMM 64x64 tile (Wo / FFN2): TLP for latency-bound shapes ----
// Grid = 8 XCD x 16 row-panels x GX cols = 1024 blocks -> 4 blocks/CU.
// 4-slot ring, vmcnt(4) = 2-step depth. xcd=fid&7, col=s%GX, panel=xcd*16+s/GX.
template<int FLAGS, int GX>
__global__ __launch_bounds__(256) void gemm_m64(
    const u16* __restrict__ A, const u16* __restrict__ BT,
    const int N, const int K,
    const float* __restrict__ bias, const float* __restrict__ res,
    void* __restrict__ outv)
{
    __shared__ __attribute__((aligned(16))) u16 As[4 * 2048];
    __shared__ __attribute__((aligned(16))) u16 Bs[4 * 2048];
    const int fid = blockIdx.x;
    const int xcd = fid & 7, s8 = fid >> 3;
    const int colb = s8 % GX, rl = s8 / GX;
    const int m0 = (xcd*16 + rl) << 6;
    const int n0 = colb << 6;
    const int tid = threadIdx.x, lane = tid & 63, w = tid >> 6;
    const int g = lane >> 4, c = lane & 15;
    const f32x4 fz = {0.f, 0.f, 0.f, 0.f};

    f32x4 acc[4] = {fz, fz, fz, fz};

    const int srow = tid >> 2;
    const int scs = (((tid & 3) ^ (srow & 3)) * 8);
    const u16* Ag = A  + (size_t)(m0 + srow)*K + scs;
    const u16* Bg = BT + (size_t)(n0 + srow)*K + scs;

    const int nkt = K >> 5;
    auto stage = [&](int slot, int kt) {
        const int k0 = kt << 5;
        gload16(Ag + k0, &As[0] + slot*2048 + w*512);
        gload16(Bg + k0, &Bs[0] + slot*2048 + w*512);
    };
    stage(0, 0);
    stage(1, (1 < nkt) ? 1 : 0);
    stage(2, (2 < nkt) ? 2 : 0);

    const int arow = w*16 + c;
    const int aoff = arow*32 + ((g ^ (arow & 3)) * 8);
    for (int kt = 0; kt < nkt; ++kt) {
        asm volatile("s_waitcnt vmcnt(4)" ::: "memory");
        __builtin_amdgcn_s_barrier();
        asm volatile("" ::: "memory");
        {
            int tp = kt + 3; if (tp >= nkt) tp = nkt - 1;
            stage((kt + 3) & 3, tp);
        }
        const int rd = kt & 3;
        const u16* Ab = &As[0] + rd*2048;
        const u16* Bb = &Bs[0] + rd*2048;
        const bf16x8 af = *(const bf16x8*)(Ab + aoff);
        bf16x8 bfr[4];
        #pragma unroll
        for (int n = 0; n < 4; ++n) {
            const int row = n*16 + c;
            bfr[n] = *(const bf16x8*)(Bb + row*32 + ((g ^ (row & 3)) * 8));
        }
        #pragma unroll
        for (int n = 0; n < 4; ++n)
            acc[n] = __builtin_amdgcn_mfma_f32_16x16x32_bf16(af, bfr[n], acc[n], 0, 0, 0);
    }

    const int row = m0 + w*16 + 4*g;
    #pragma unroll
    for (int n = 0; n < 4; ++n) {
        const int col = n0 + n*16 + c;
        const float bv = (FLAGS & 1) ? bias[col] : 0.0f;
        #pragma unroll
        for (int r = 0; r < 4; ++r) {
            float v = acc[n][r] + bv;
            if (FLAGS & 2) v += res[(size_t)(row + r)*N + col];
            if (FLAGS & 4) v = fmaxf(v, 0.0f);
            if (FLAGS & 8) ((float*)outv)[(size_t)(row + r)*N + col] = v;
            else           ((u16*)outv)[(size_t)(row + r)*N + col] = f2b(v);
        }
    }
}

// ---------------- causal flash attention, barrier-free kv loop -----------------
// grid (160, 16) flattened: fid -> xcd = fid&7, each XCD owns 2 bh (K/V L2-pinned);
// longest chunks first; 1/2/3/4-way balanced kv-split (max 16 tiles/block).
// Q tile (64x64) staged once in LDS (XOR chunk^=row&7). K and V rings 2 slots
// each (depth 1; K/V L2-resident). Per iter: issue {V,K}(t+1), wait vmcnt(4) ==
// drain exactly {V,K}(t). LDS 40KB. launch_bounds (256,4): cap unified regs at
// 128 (64 arch + 64 AGPR) -> 4 blocks/CU. Deficit vs free allocation is only
// 8 VGPRs (R17: 72) -> remat range, unlike R11's 20-reg oacc spill.
__global__ __launch_bounds__(256, 4) void attn_fwd(
    const u16* __restrict__ qkv, const u16* __restrict__ vT,
    u16* __restrict__ part, u16* __restrict__ att)
{
    const int fid = blockIdx.x + 160 * blockIdx.y;
    const int xcd = fid & 7, s0i = fid >> 3;
    const int half = (s0i >= 160) ? 1 : 0;
    const int bh = xcd*2 + half, b = bh >> 3, h = bh & 7;
    const int i = 159 - (s0i - half*160);          // longest-first
    int qt, cch, nch;
    if (i < 16)      { qt = i;                         cch = 0;          nch = 1; }
    else if (i < 48) { int j = i-16; qt = 16 + (j>>1); cch = j & 1;      nch = 2; }
    else if (i < 96) { int j = i-48; int d3 = j/3; qt = 32 + d3; cch = j - 3*d3; nch = 3; }
    else             { int j = i-96; qt = 48 + (j>>2); cch = j & 3;      nch = 4; }
    const int ntl = qt + 1;
    const int t0 = (cch * ntl) / nch;
    const int t1 = ((cch + 1) * ntl) / nch;
    const int single = (nch == 1);

    const int tid = threadIdx.x, lane = tid & 63, w = tid >> 6;
    const int g = lane >> 4, c16 = lane & 15;
    // 40KB: rings 32KB [0,16384) u16 (per-wave 4096: K 2x1024 @0, V 2x1024 @2048);
    // Q 8KB [16384,20480) u16. Epilogue reuse of rings: img 4x1280 f32 @[0,20480B),
    // lbuf 256 f32 @[20480,21504B).
    __shared__ __attribute__((aligned(16))) u16 smem[20480];
    u16* Wb = smem + w*4096;
    u16* Qs = smem + 16384;
    float* lbuf = (float*)smem + 5120;

    const u16* qp  = qkv + (size_t)b*4096*1536 + h*64;
    const u16* kp  = qp + 512;
    const u16* vtp = vT + (size_t)bh*64*4096;

    const u16* kgA = kp + (size_t)(16*w + (lane>>3))*1536
                        + (((lane&7) ^ ((lane>>3)&7)) * 8);
    const u16* kgB = kgA + (size_t)8*1536;
    const int sd = lane >> 1;
    const u16* vgA = vtp + (size_t)sd*4096 + 16*w + (((lane&1) ^ ((sd>>2)&1)) * 8);
    const u16* vgB = vgA + (size_t)32*4096;

    const int kOff0 = c16*64 + ((g ^ (c16&7)) * 8);
    const int kOff1 = c16*64 + (((4+g) ^ (c16&7)) * 8);
    const int vroff = c16*16 + (((g>>1) ^ ((c16>>2)&1)) * 8) + (g&1)*4;

    const int Q0 = qt*64;
    // ---- stage Q tile into LDS, swizzled (chunk ^= row&7) ----
    {
        const int qrow = tid >> 2;
        const int ch0 = (tid & 3) * 2, ch1 = ch0 + 1;
        const u16* qsrc = qp + (size_t)(Q0 + qrow)*1536 + ch0*8;
        u16x8 d0 = *(const u16x8*)(qsrc);
        u16x8 d1 = *(const u16x8*)(qsrc + 8);
        *(u16x8*)(Qs + qrow*64 + ((ch0 ^ (qrow&7))*8)) = d0;
        *(u16x8*)(Qs + qrow*64 + ((ch1 ^ (qrow&7))*8)) = d1;
    }
    __syncthreads();   // Q visible to all waves (also drains vmcnt: rings not yet issued)

    const f32x4 fz = {0.f,0.f,0.f,0.f};
    f32x4 oacc[4][4];   // [dt][sub]: O^T[d=dt*16+4g+r][q=sub*16+c16]
    #pragma unroll
    for (int dt = 0; dt < 4; ++dt)
      #pragma unroll
      for (int sub = 0; sub < 4; ++sub) oacc[dt][sub] = fz;
    float lsum[4] = {0.f, 0.f, 0.f, 0.f};

    // prologue: V(t0), K(t0) into slots t0&1
    {
        const int kv0 = t0 << 6;
        u16* vd = Wb + 2048 + (t0 & 1)*1024;
        gload16(vgA + kv0, vd); gload16(vgB + kv0, vd + 512);
        u16* kd = Wb + (t0 & 1)*1024;
        const size_t ko0 = (size_t)kv0 * 1536;
        gload16(kgA + ko0, kd); gload16(kgB + ko0, kd + 512);
    }

    for (int t = t0; t < t1; ++t) {
        // issue V(t+1), K(t+1) (clamped; uniform 4 issues/iter)
        {
            const int tp = (t+1 < t1) ? (t+1) : (t1-1);
            const int kv = tp << 6;
            u16* vd = Wb + 2048 + ((t+1) & 1)*1024;
            gload16(vgA + kv, vd); gload16(vgB + kv, vd + 512);
            u16* kd = Wb + ((t+1) & 1)*1024;
            const size_t ko = (size_t)kv * 1536;
            gload16(kgA + ko, kd); gload16(kgB + ko, kd + 512);
        }
        // keep 4 newest = {V,K}(t+1); drains {V,K}(t)
        asm volatile("s_waitcnt vmcnt(4)" ::: "memory");
        const u16* Kb  = Wb + (t & 1)*1024;
        const u16* Vbp = Wb + 2048 + (t & 1)*1024;
        const bf16x8 kc0 = *(const bf16x8*)(Kb + kOff0);
        const bf16x8 kc1 = *(const bf16x8*)(Kb + kOff1);
        bf16x4 va[4];
        #pragma unroll
        for (int dt = 0; dt < 4; ++dt)
            va[dt] = *(const bf16x4*)(Vbp + dt*256 + vroff);
        // ---- S^T[strip kv][64 q], Q fragments from LDS ----
        f32x4 s[4];
        #pragma unroll
        for (int sub = 0; sub < 4; ++sub) {
            const int qrow = sub*16 + c16;
            const bf16x8 qb0 = *(const bf16x8*)(Qs + qrow*64 + ((g ^ (c16&7))*8));
            const bf16x8 qb1 = *(const bf16x8*)(Qs + qrow*64 + (((4+g) ^ (c16&7))*8));
            f32x4 sv = __builtin_amdgcn_mfma_f32_16x16x32_bf16(kc0, qb0, fz, 0, 0, 0);
            s[sub]   = __builtin_amdgcn_mfma_f32_16x16x32_bf16(kc1, qb1, sv, 0, 0, 0);
        }
        // ---- softmax numerator (exp2, static max 0), in-register P^T ----
        bf16x4 pt[4];
        if (t < qt) {
            #pragma unroll
            for (int sub = 0; sub < 4; ++sub) {
                float p0 = fexp2(s[sub][0]), p1 = fexp2(s[sub][1]);
                float p2 = fexp2(s[sub][2]), p3 = fexp2(s[sub][3]);
                lsum[sub] += (p0 + p1) + (p2 + p3);
                bf16x4 pv;
                pv[0] = (__bf16)p0; pv[1] = (__bf16)p1;
                pv[2] = (__bf16)p2; pv[3] = (__bf16)p3;
                pt[sub] = pv;
            }
        } else {  // diagonal tile: causal mask
            const int kvbase = t*64 + 16*w + 4*g;
            #pragma unroll
            for (int sub = 0; sub < 4; ++sub) {
                const int qi = Q0 + sub*16 + c16;
                bf16x4 pv; float a = 0.f;
                #pragma unroll
                for (int r = 0; r < 4; ++r) {
                    float p = (kvbase + r <= qi) ? fexp2(s[sub][r]) : 0.0f;
                    a += p; pv[r] = (__bf16)p;
                }
                lsum[sub] += a; pt[sub] = pv;
            }
        }
        // ---- O^T += V^T . P^T ----
        #pragma unroll
        for (int dt = 0; dt < 4; ++dt)
          #pragma unroll
          for (int sub = 0; sub < 4; ++sub)
            oacc[dt][sub] = mfma16(va[dt], pt[sub], oacc[dt][sub]);
    }

    // ---- l totals (register shuffle reduce) ----
    #pragma unroll
    for (int sub = 0; sub < 4; ++sub) {
        float v = lsum[sub];
        v += __shfl_xor(v, 16);
        v += __shfl_xor(v, 32);
        lsum[sub] = v;
    }

    // drain own tail DMAs before smem is repurposed, then block-sync
    asm volatile("s_waitcnt vmcnt(0)" ::: "memory");
    __syncthreads();
    #pragma unroll
    for (int sub = 0; sub < 4; ++sub)
        if (g == 0) lbuf[w*64 + sub*16 + c16] = lsum[sub];

    // ---- cross-wave O reduce: 4 STATIC rounds; wave dt collects d-slice dt ----
    float* img = (float*)smem;   // 4 regions x 1280 f32: [wave][64q x stride20]
    f32x4 ofin[4];
    float ltot[4];
    #pragma unroll
    for (int dt = 0; dt < 4; ++dt) {
        #pragma unroll
        for (int sub = 0; sub < 4; ++sub)
            *(f32x4*)(img + w*1280 + (sub*16 + c16)*20 + g*4) = oacc[dt][sub];
        __syncthreads();
        if (dt == 0) {
            #pragma unroll
            for (int sub = 0; sub < 4; ++sub) {
                const int qr = sub*16 + c16;
                ltot[sub] = lbuf[qr] + lbuf[64 + qr] + lbuf[128 + qr] + lbuf[192 + qr];
            }
        }
        if (w == dt) {
            #pragma unroll
            for (int sub = 0; sub < 4; ++sub) {
                const int off = (sub*16 + c16)*20 + g*4;
                f32x4 a0 = *(const f32x4*)(img + off);
                f32x4 a1 = *(const f32x4*)(img + 1280 + off);
                f32x4 a2 = *(const f32x4*)(img + 2560 + off);
                f32x4 a3 = *(const f32x4*)(img + 3840 + off);
                ofin[sub] = (a0 + a1) + (a2 + a3);
            }
        }
        __syncthreads();
    }

    // ---- store: wave w owns d in [16w, 16w+16) ----
    const int dbase = 16*w + 4*g;
    if (single) {
        #pragma unroll
        for (int sub = 0; sub < 4; ++sub) {
            const int qrow = sub*16 + c16;
            const float inv = 1.0f / ltot[sub];
            const f32x4 o = ofin[sub];
            u16x4 ov;
            ov[0] = f2b(o[0]*inv); ov[1] = f2b(o[1]*inv);
            ov[2] = f2b(o[2]*inv); ov[3] = f2b(o[3]*inv);
            *(u16x4*)(att + (size_t)(b*4096 + Q0 + qrow)*512 + h*64 + dbase) = ov;
        }
    } else {
        u16* onum = part + (size_t)(bh*160 + i) * 4224;   // 8448 B/slot
        float* lout = (float*)(onum + 4096);
        #pragma unroll
        for (int sub = 0; sub < 4; ++sub) {
            const int qrow = sub*16 + c16;
            const f32x4 o = ofin[sub];
            u16x4 ov;
            ov[0] = f2b(o[0]); ov[1] = f2b(o[1]);
            ov[2] = f2b(o[2]); ov[3] = f2b(o[3]);
            *(u16x4*)(onum + qrow*64 + dbase) = ov;
            if (w == 0 && g == 0) lout[qrow] = ltot[sub];
        }
    }
}

// ---------------- merge 2/3/4 split-kv partials (q-tiles 16..63) --------------
__global__ __launch_bounds__(256) void attn_merge(
    const u16* __restrict__ part, u16* __restrict__ att)
{
    const int qt = 16 + blockIdx.x, bh = blockIdx.y, b = bh >> 3, h = bh & 7;
    int start, n;
    if (qt < 32)      { start = 16 + 2*(qt-16); n = 2; }
    else if (qt < 48) { start = 48 + 3*(qt-32); n = 3; }
    else              { start = 96 + 4*(qt-48); n = 4; }
    const int t = threadIdx.x;
    const int row = t >> 2, c0 = (t & 3) * 16;
    float acc[16];
    #pragma unroll
    for (int j = 0; j < 16; ++j) acc[j] = 0.f;
    float lt = 0.f;
    const u16* p0 = part + (size_t)(bh*160 + start) * 4224;
    for (int ci = 0; ci < n; ++ci) {
        const u16* pc = p0 + (size_t)ci * 4224;
        lt += ((const float*)(pc + 4096))[row];
        u16x8 a = *(const u16x8*)(pc + row*64 + c0);
        u16x8 bq = *(const u16x8*)(pc + row*64 + c0 + 8);
        #pragma unroll
        for (int j = 0; j < 8; ++j) { acc[j] += b2f(a[j]); acc[8+j] += b2f(bq[j]); }
    }
    const float inv = 1.0f / lt;
    u16x8 o1, o2;
    #pragma unroll
    for (int j = 0; j < 8; ++j) { o1[j] = f2b(acc[j]*inv); o2[j] = f2b(acc[8+j]*inv); }
    u16* dst = att + (size_t)(b*4096 + qt*64 + row)*512 + h*64 + c0;
    *(u16x8*)dst = o1;
    *(u16x8*)(dst + 8) = o2;
}

// -------------------------------------------------------------------------------
extern "C" void kernel_launch(void* const* d_in, const int* in_sizes, int n_in,
                              void* d_out, int out_size, void* d_ws, size_t ws_size,
                              hipStream_t stream)
{
    (void)in_sizes; (void)n_in; (void)out_size; (void)ws_size;
    const float* x   = (const float*)d_in[0];
    const float* Wq  = (const float*)d_in[1];
    const float* Wk  = (const float*)d_in[2];
    const float* Wv  = (const float*)d_in[3];
    const float* Wo  = (const float*)d_in[4];
    const float* bo  = (const float*)d_in[5];
    const float* W1  = (const float*)d_in[6];
    const float* b1  = (const float*)d_in[7];
    const float* W2  = (const float*)d_in[8];
    const float* b2  = (const float*)d_in[9];
    const float* g1  = (const float*)d_in[10];
    const float* be1 = (const float*)d_in[11];
    const float* g2  = (const float*)d_in[12];
    const float* be2 = (const float*)d_in[13];

    char* ws = (char*)d_ws;
    u16*   WqkvT = (u16*)(ws + 0);
    u16*   WoT   = (u16*)(ws + 1572864);
    u16*   W1T   = (u16*)(ws + 2097152);
    u16*   W2T   = (u16*)(ws + 4194304);
    u16*   H     = (u16*)(ws + 6291456);    // ln1/ln2 out [8192][512] bf16
    u16*   PART  = (u16*)(ws + 6291456);    // attn partials 160/bh x16 x8448B =21.6MB
                                            // (H dead; consumed by merge before Wo writes X2)
    float* X2    = (float*)(ws + 14680064); // post-attention residual (f32)
    u16*   QKV   = (u16*)(ws + 31457280);   // [8192][1536] (V cols unwritten)
    u16*   VT    = (u16*)(ws + 56623104);   // [1024][4096], from QKV-gemm epilogue
    u16*   ATT   = (u16*)(ws + 65011712);   // [8192][512]
    u16*   F1    = (u16*)(ws + 31457280);   // [8192][2048], reuses QKV+VT

    prep_w<<<3072, 256, 0, stream>>>(Wq, Wk, Wv, Wo, W1, W2,
                                     WqkvT, WoT, W1T, W2T);
    ln_rows<<<2048, 256, 0, stream>>>(x, g1, be1, H);
    gemm_bt<48, 2, 12><<<768, 256, 0, stream>>>(H, WqkvT, 1536, 512,
                                                nullptr, nullptr, QKV, VT);
    attn_fwd<<<dim3(160, 16), 256, 0, stream>>>(QKV, VT, PART, ATT);
    attn_merge<<<dim3(48, 16), 256, 0, stream>>>(PART, ATT);
    gemm_m64<11, 8><<<1024, 256, 0, stream>>>(ATT, WoT, 512, 512,
                                              bo, x, X2);
    ln_rows<<<2048, 256, 0, stream>>>(X2, g2, be2, H);
    gemm_bt<5, 2, 16><<<1024, 256, 0, stream>>>(H, W1T, 2048, 512,
                                                b1, nullptr, F1, nullptr);
    gemm_m64<11, 8><<<1024, 256, 0, stream>>>(F1, W2T, 512, 2048,
                                              b2, X2, (float*)d_out);
}

// Round 19
// 187.747 us; speedup vs baseline: 1.0364x; 1.0364x over previous
//
#include <hip/hip_runtime.h>

typedef __attribute__((ext_vector_type(8))) __bf16 bf16x8;
typedef __attribute__((ext_vector_type(4))) __bf16 bf16x4;
typedef __attribute__((ext_vector_type(4))) float f32x4;
typedef __attribute__((ext_vector_type(4))) unsigned int u32x4;
typedef __attribute__((ext_vector_type(4))) unsigned short u16x4;
typedef __attribute__((ext_vector_type(8))) unsigned short u16x8;
typedef __attribute__((ext_vector_type(4))) short s16x4;
typedef unsigned short u16;

static __device__ __forceinline__ u16 f2b(float f) {
    unsigned u = __builtin_bit_cast(unsigned, f);
    u = (u + 0x7FFFu + ((u >> 16) & 1u)) >> 16;
    return (u16)u;
}
static __device__ __forceinline__ float b2f(u16 u) {
    return __builtin_bit_cast(float, ((unsigned)u) << 16);
}
static __device__ __forceinline__ float fexp2(float x) {
#if __has_builtin(__builtin_amdgcn_exp2f)
    return __builtin_amdgcn_exp2f(x);
#else
    return exp2f(x);
#endif
}
static __device__ __forceinline__ f32x4 mfma16(bf16x4 a, bf16x4 b, f32x4 c) {
#if __has_builtin(__builtin_amdgcn_mfma_f32_16x16x16_bf16)
    return __builtin_amdgcn_mfma_f32_16x16x16_bf16(a, b, c, 0, 0, 0);
#else
    return __builtin_amdgcn_mfma_f32_16x16x16bf16_1k(
        __builtin_bit_cast(s16x4, a), __builtin_bit_cast(s16x4, b), c, 0, 0, 0);
#endif
}

// async global->LDS, 16B per lane; LDS dest = wave-uniform base + lane*16
static __device__ __forceinline__ void gload16(const u16* g, u16* l) {
    __builtin_amdgcn_global_load_lds(
        (const __attribute__((address_space(1))) unsigned int*)g,
        (__attribute__((address_space(3))) unsigned int*)l, 16, 0, 0);
}

// ---------------- weight transpose+convert: src[K][N] f32 -> dst[N][K] bf16 ----
__global__ __launch_bounds__(256) void prep_w(
    const float* __restrict__ Wq, const float* __restrict__ Wk,
    const float* __restrict__ Wv, const float* __restrict__ Wo,
    const float* __restrict__ W1, const float* __restrict__ W2,
    u16* __restrict__ WqkvT, u16* __restrict__ WoT,
    u16* __restrict__ W1T, u16* __restrict__ W2T)
{
    const int i = blockIdx.x;
    const float* src; u16* dst; int K, N, nt, kt;
    if (i < 1024) {
        const int z = i >> 8, idx = i & 255;
        K = 512; N = 512; nt = (idx & 15) * 32; kt = (idx >> 4) * 32;
        if (z == 0)      { src = Wq; dst = WqkvT; }
        else if (z == 1) { src = Wk; dst = WqkvT + 512*512; }
        else if (z == 2) { src = Wv; dst = WqkvT + 1024*512; }
        else             { src = Wo; dst = WoT; }
    } else if (i < 2048) {
        const int idx = i - 1024;
        src = W1; dst = W1T; K = 512; N = 2048;
        nt = (idx & 63) * 32; kt = (idx >> 6) * 32;
    } else {
        const int idx = i - 2048;
        src = W2; dst = W2T; K = 2048; N = 512;
        nt = (idx & 15) * 32; kt = (idx >> 4) * 32;
    }
    __shared__ float tile[32][33];
    const int tx = threadIdx.x & 31, ty = threadIdx.x >> 5;
    #pragma unroll
    for (int r = 0; r < 4; ++r)
        tile[ty + r*8][tx] = src[(size_t)(kt + ty + r*8) * N + nt + tx];
    __syncthreads();
    #pragma unroll
    for (int r = 0; r < 4; ++r)
        dst[(size_t)(nt + ty + r*8) * K + kt + tx] = f2b(tile[tx][ty + r*8]);
}

// ---------------- LayerNorm rows: [8192][512] f32 -> bf16 ----------------------
__global__ __launch_bounds__(256) void ln_rows(
    const float* __restrict__ x, const float* __restrict__ g,
    const float* __restrict__ b, u16* __restrict__ out)
{
    const int row = blockIdx.x * 4 + (threadIdx.x >> 6);
    const int lane = threadIdx.x & 63;
    const float* xr = x + (size_t)row * 512;
    f32x4 v0 = *(const f32x4*)(xr + lane * 4);
    f32x4 v1 = *(const f32x4*)(xr + 256 + lane * 4);
    float s = v0[0]+v0[1]+v0[2]+v0[3]+v1[0]+v1[1]+v1[2]+v1[3];
    #pragma unroll
    for (int o = 1; o < 64; o <<= 1) s += __shfl_xor(s, o);
    const float mu = s * (1.0f / 512.0f);
    float s2 = 0.f;
    #pragma unroll
    for (int i = 0; i < 4; ++i) { float d0 = v0[i]-mu, d1 = v1[i]-mu; s2 += d0*d0 + d1*d1; }
    #pragma unroll
    for (int o = 1; o < 64; o <<= 1) s2 += __shfl_xor(s2, o);
    const float inv = rsqrtf(s2 * (1.0f/512.0f) + 1e-5f);
    f32x4 g0 = *(const f32x4*)(g + lane*4), g1 = *(const f32x4*)(g + 256 + lane*4);
    f32x4 b0 = *(const f32x4*)(b + lane*4), b1 = *(const f32x4*)(b + 256 + lane*4);
    u16x4 p0, p1;
    #pragma unroll
    for (int i = 0; i < 4; ++i) {
        p0[i] = f2b((v0[i]-mu)*inv*g0[i] + b0[i]);
        p1[i] = f2b((v1[i]-mu)*inv*g1[i] + b1[i]);
    }
    u16* orow = out + (size_t)row * 512;
    *(u16x4*)(orow + lane*4)       = p0;
    *(u16x4*)(orow + 256 + lane*4) = p1;
}

// ---------------- GEMM 128xN tile (QKV / FFN1) ---------------------------------
// FLAGS: 1=bias, 2=residual(f32), 4=relu, 8=store f32 (else bf16),
//        16=scale cols<512 by 512^-0.5*log2(e), 32=cols>=1024 -> write V^T to vt
// GX = grid cols. 1D grid, XCD-aware: xcd=fid&7, s=fid>>3, col=s%GX, row=xcd*8+s/GX.
// NB=2: 3-slot ring, vmcnt(4). Counted vmcnt + raw s_barrier; stage AFTER barrier.
template<int FLAGS, int NB, int GX>
__global__ __launch_bounds__(256) void gemm_bt(
    const u16* __restrict__ A, const u16* __restrict__ BT,
    const int N, const int K,
    const float* __restrict__ bias, const float* __restrict__ res,
    void* __restrict__ outv, u16* __restrict__ vt)
{
    constexpr int RING = (NB == 2) ? 3 : 4;
    __shared__ __attribute__((aligned(16))) u16 As[RING * 4096];
    __shared__ __attribute__((aligned(16))) u16 Bs[RING * 2048 * NB];
    const int fid = blockIdx.x;
    const int xcd = fid & 7, s8 = fid >> 3;
    const int colb = s8 % GX, rl = s8 / GX;
    const int m0 = (xcd*8 + rl) << 7;
    const int n0 = colb * (64 * NB);
    const int tid = threadIdx.x, lane = tid & 63, w = tid >> 6;
    const int wr2 = w >> 1, wc = w & 1;
    const int g = lane >> 4, c = lane & 15;
    const f32x4 fz = {0.f, 0.f, 0.f, 0.f};

    f32x4 acc[4][2 * NB];
    #pragma unroll
    for (int m = 0; m < 4; ++m)
      #pragma unroll
      for (int n = 0; n < 2 * NB; ++n) acc[m][n] = fz;

    const int srow = tid >> 2;
    const int scs = (((tid & 3) ^ (srow & 3)) * 8);
    const u16* Ag = A  + (size_t)(m0 + srow)*K + scs;
    const u16* Bg = BT + (size_t)(n0 + srow)*K + scs;
    const size_t rstep = (size_t)64 * K;

    const int nkt = K >> 5;
    auto stage = [&](int slot, int kt) {
        const int k0 = kt << 5;
        u16* ad = &As[0] + slot*4096 + w*512;
        gload16(Ag + k0,         ad);
        gload16(Ag + rstep + k0, ad + 2048);
        u16* bd = &Bs[0] + slot*2048*NB + w*512;
        gload16(Bg + k0, bd);
        if constexpr (NB == 2) gload16(Bg + rstep + k0, bd + 2048);
    };
    stage(0, 0);
    stage(1, (1 < nkt) ? 1 : 0);
    if constexpr (RING == 4) stage(2, (2 < nkt) ? 2 : 0);

    for (int kt = 0; kt < nkt; ++kt) {
        if constexpr (NB == 2) asm volatile("s_waitcnt vmcnt(4)" ::: "memory");
        else                   asm volatile("s_waitcnt vmcnt(6)" ::: "memory");
        __builtin_amdgcn_s_barrier();
        asm volatile("" ::: "memory");
        {
            int tp = kt + RING - 1; if (tp >= nkt) tp = nkt - 1;
            int sl = kt + RING - 1; sl -= (sl / RING) * RING;
            stage(sl, tp);
        }
        const int rd = kt - (kt / RING) * RING;
        const u16* Ab = &As[0] + rd*4096;
        const u16* Bb = &Bs[0] + rd*2048*NB;
        bf16x8 af[4], bfr[2 * NB];
        #pragma unroll
        for (int m = 0; m < 4; ++m) {
            const int row = wr2*64 + m*16 + c;
            af[m] = *(const bf16x8*)(Ab + row*32 + (((g*16) ^ ((row&3)<<4)) >> 1));
        }
        #pragma unroll
        for (int n = 0; n < 2 * NB; ++n) {
            const int row = wc*(32*NB) + n*16 + c;
            bfr[n] = *(const bf16x8*)(Bb + row*32 + (((g*16) ^ ((row&3)<<4)) >> 1));
        }
        #pragma unroll
        for (int m = 0; m < 4; ++m)
          #pragma unroll
          for (int n = 0; n < 2 * NB; ++n)
            acc[m][n] = __builtin_amdgcn_mfma_f32_16x16x32_bf16(af[m], bfr[n], acc[m][n], 0, 0, 0);
    }

    #pragma unroll
    for (int m = 0; m < 4; ++m) {
        const int row = m0 + wr2*64 + m*16 + 4*g;
        #pragma unroll
        for (int n = 0; n < 2 * NB; ++n) {
            const int col = n0 + wc*(32*NB) + n*16 + c;
            const float bv = (FLAGS & 1) ? bias[col] : 0.0f;
            float vv[4];
            #pragma unroll
            for (int r = 0; r < 4; ++r) {
                float v = acc[m][n][r] + bv;
                if (FLAGS & 16) v *= (col < 512) ? 0.0637587246f : 1.0f;
                if (FLAGS & 2) v += res[(size_t)(row + r)*N + col];
                if (FLAGS & 4) v = fmaxf(v, 0.0f);
                vv[r] = v;
            }
            if ((FLAGS & 32) && col >= 1024) {
                u16x4 pv;
                #pragma unroll
                for (int r = 0; r < 4; ++r) pv[r] = f2b(vv[r]);
                *(u16x4*)(vt + (size_t)((row >> 12)*512 + (col - 1024))*4096
                             + (row & 4095)) = pv;
            } else if (FLAGS & 8) {
                #pragma unroll
                for (int r = 0; r < 4; ++r)
                    ((float*)outv)[(size_t)(row + r)*N + col] = vv[r];
            } else {
                #pragma unroll
                for (int r = 0; r < 4; ++r)
                    ((u16*)outv)[(size_t)(row + r)*N + col] = f2b(vv[r]);
            }
        }
    }
}

// ---------------- GEMM 64x64 tile (Wo / FFN2): TLP for latency-bound shapes ----
// Grid = 8 XCD x 16 row-panels x GX cols = 1024 blocks -> 4 blocks/CU.
// 4-slot ring, vmcnt(4) = 2-step depth. xcd=fid&7, col=s%GX, panel=xcd*16+s/GX.
template<int FLAGS, int GX>
__global__ __launch_bounds__(256) void gemm_m64(
    const u16* __restrict__ A, const u16* __restrict__ BT,
    const int N, const int K,
    const float* __restrict__ bias, const float* __restrict__ res,
    void* __restrict__ outv)
{
    __shared__ __attribute__((aligned(16))) u16 As[4 * 2048];
    __shared__ __attribute__((aligned(16))) u16 Bs[4 * 2048];
    const int fid = blockIdx.x;
    const int xcd = fid & 7, s8 = fid >> 3;
    const int colb = s8 % GX, rl = s8 / GX;
    const int m0 = (xcd*16 + rl) << 6;
    const int n0 = colb << 6;
    const int tid = threadIdx.x, lane = tid & 63, w = tid >> 6;
    const int g = lane >> 4, c = lane & 15;
    const f32x4 fz = {0.f, 0.f, 0.f, 0.f};

    f32x4 acc[4] = {fz, fz, fz, fz};

    const int srow = tid >> 2;
    const int scs = (((tid & 3) ^ (srow & 3)) * 8);
    const u16* Ag = A  + (size_t)(m0 + srow)*K + scs;
    const u16* Bg = BT + (size_t)(n0 + srow)*K + scs;

    const int nkt = K >> 5;
    auto stage = [&](int slot, int kt) {
        const int k0 = kt << 5;
        gload16(Ag + k0, &As[0] + slot*2048 + w*512);
        gload16(Bg + k0, &Bs[0] + slot*2048 + w*512);
    };
    stage(0, 0);
    stage(1, (1 < nkt) ? 1 : 0);
    stage(2, (2 < nkt) ? 2 : 0);

    const int arow = w*16 + c;
    const int aoff = arow*32 + ((g ^ (arow & 3)) * 8);
    for (int kt = 0; kt < nkt; ++kt) {
        asm volatile("s_waitcnt vmcnt(4)" ::: "memory");
        __builtin_amdgcn_s_barrier();
        asm volatile("" ::: "memory");
        {
            int tp = kt + 3; if (tp >= nkt) tp = nkt - 1;
            stage((kt + 3) & 3, tp);
        }
        const int rd = kt & 3;
        const u16* Ab = &As[0] + rd*2048;
        const u16* Bb = &Bs[0] + rd*2048;
        const bf16x8 af = *(const bf16x8*)(Ab + aoff);
        bf16x8 bfr[4];
        #pragma unroll
        for (int n = 0; n < 4; ++n) {
            const int row = n*16 + c;
            bfr[n] = *(const bf16x8*)(Bb + row*32 + ((g ^ (row & 3)) * 8));
        }
        #pragma unroll
        for (int n = 0; n < 4; ++n)
            acc[n] = __builtin_amdgcn_mfma_f32_16x16x32_bf16(af, bfr[n], acc[n], 0, 0, 0);
    }

    const int row = m0 + w*16 + 4*g;
    #pragma unroll
    for (int n = 0; n < 4; ++n) {
        const int col = n0 + n*16 + c;
        const float bv = (FLAGS & 1) ? bias[col] : 0.0f;
        #pragma unroll
        for (int r = 0; r < 4; ++r) {
            float v = acc[n][r] + bv;
            if (FLAGS & 2) v += res[(size_t)(row + r)*N + col];
            if (FLAGS & 4) v = fmaxf(v, 0.0f);
            if (FLAGS & 8) ((float*)outv)[(size_t)(row + r)*N + col] = v;
            else           ((u16*)outv)[(size_t)(row + r)*N + col] = f2b(v);
        }
    }
}

// ---------------- causal flash attention, barrier-free kv loop -----------------
// grid (160, 16) flattened: fid -> xcd = fid&7, each XCD owns 2 bh (K/V L2-pinned);
// longest chunks first; 1/2/3/4-way balanced kv-split (max 16 tiles/block).
// Q tile (64x64) staged once in LDS (XOR chunk^=row&7). K and V rings 2 slots
// each (depth 1; K/V L2-resident). Per iter: issue {V,K}(t+1), wait vmcnt(4) ==
// drain exactly {V,K}(t). LDS 40KB. launch_bounds (256,3): best measured config
// (R17, 67us); (256,4) forced VGPR 64 and loop-spilled (R18: WRITE 21->39MB).
__global__ __launch_bounds__(256, 3) void attn_fwd(
    const u16* __restrict__ qkv, const u16* __restrict__ vT,
    u16* __restrict__ part, u16* __restrict__ att)
{
    const int fid = blockIdx.x + 160 * blockIdx.y;
    const int xcd = fid & 7, s0i = fid >> 3;
    const int half = (s0i >= 160) ? 1 : 0;
    const int bh = xcd*2 + half, b = bh >> 3, h = bh & 7;
    const int i = 159 - (s0i - half*160);          // longest-first
    int qt, cch, nch;
    if (i < 16)      { qt = i;                         cch = 0;          nch = 1; }
    else if (i < 48) { int j = i-16; qt = 16 + (j>>1); cch = j & 1;      nch = 2; }
    else if (i < 96) { int j = i-48; int d3 = j/3; qt = 32 + d3; cch = j - 3*d3; nch = 3; }
    else             { int j = i-96; qt = 48 + (j>>2); cch = j & 3;      nch = 4; }
    const int ntl = qt + 1;
    const int t0 = (cch * ntl) / nch;
    const int t1 = ((cch + 1) * ntl) / nch;
    const int single = (nch == 1);

    const int tid = threadIdx.x, lane = tid & 63, w = tid >> 6;
    const int g = lane >> 4, c16 = lane & 15;
    // 40KB: rings 32KB [0,16384) u16 (per-wave 4096: K 2x1024 @0, V 2x1024 @2048);
    // Q 8KB [16384,20480) u16. Epilogue reuse of rings: img 4x1280 f32 @[0,20480B),
    // lbuf 256 f32 @[20480,21504B).
    __shared__ __attribute__((aligned(16))) u16 smem[20480];
    u16* Wb = smem + w*4096;
    u16* Qs = smem + 16384;
    float* lbuf = (float*)smem + 5120;

    const u16* qp  = qkv + (size_t)b*4096*1536 + h*64;
    const u16* kp  = qp + 512;
    const u16* vtp = vT + (size_t)bh*64*4096;

    const u16* kgA = kp + (size_t)(16*w + (lane>>3))*1536
                        + (((lane&7) ^ ((lane>>3)&7)) * 8);
    const u16* kgB = kgA + (size_t)8*1536;
    const int sd = lane >> 1;
    const u16* vgA = vtp + (size_t)sd*4096 + 16*w + (((lane&1) ^ ((sd>>2)&1)) * 8);
    const u16* vgB = vgA + (size_t)32*4096;

    const int kOff0 = c16*64 + ((g ^ (c16&7)) * 8);
    const int kOff1 = c16*64 + (((4+g) ^ (c16&7)) * 8);
    const int vroff = c16*16 + (((g>>1) ^ ((c16>>2)&1)) * 8) + (g&1)*4;

    const int Q0 = qt*64;
    // ---- stage Q tile into LDS, swizzled (chunk ^= row&7) ----
    {
        const int qrow = tid >> 2;
        const int ch0 = (tid & 3) * 2, ch1 = ch0 + 1;
        const u16* qsrc = qp + (size_t)(Q0 + qrow)*1536 + ch0*8;
        u16x8 d0 = *(const u16x8*)(qsrc);
        u16x8 d1 = *(const u16x8*)(qsrc + 8);
        *(u16x8*)(Qs + qrow*64 + ((ch0 ^ (qrow&7))*8)) = d0;
        *(u16x8*)(Qs + qrow*64 + ((ch1 ^ (qrow&7))*8)) = d1;
    }
    __syncthreads();   // Q visible to all waves (also drains vmcnt: rings not yet issued)

    const f32x4 fz = {0.f,0.f,0.f,0.f};
    f32x4 oacc[4][4];   // [dt][sub]: O^T[d=dt*16+4g+r][q=sub*16+c16]
    #pragma unroll
    for (int dt = 0; dt < 4; ++dt)
      #pragma unroll
      for (int sub = 0; sub < 4; ++sub) oacc[dt][sub] = fz;
    float lsum[4] = {0.f, 0.f, 0.f, 0.f};

    // prologue: V(t0), K(t0) into slots t0&1
    {
        const int kv0 = t0 << 6;
        u16* vd = Wb + 2048 + (t0 & 1)*1024;
        gload16(vgA + kv0, vd); gload16(vgB + kv0, vd + 512);
        u16* kd = Wb + (t0 & 1)*1024;
        const size_t ko0 = (size_t)kv0 * 1536;
        gload16(kgA + ko0, kd); gload16(kgB + ko0, kd + 512);
    }

    for (int t = t0; t < t1; ++t) {
        // issue V(t+1), K(t+1) (clamped; uniform 4 issues/iter)
        {
            const int tp = (t+1 < t1) ? (t+1) : (t1-1);
            const int kv = tp << 6;
            u16* vd = Wb + 2048 + ((t+1) & 1)*1024;
            gload16(vgA + kv, vd); gload16(vgB + kv, vd + 512);
            u16* kd = Wb + ((t+1) & 1)*1024;
            const size_t ko = (size_t)kv * 1536;
            gload16(kgA + ko, kd); gload16(kgB + ko, kd + 512);
        }
        // keep 4 newest = {V,K}(t+1); drains {V,K}(t)
        asm volatile("s_waitcnt vmcnt(4)" ::: "memory");
        const u16* Kb  = Wb + (t & 1)*1024;
        const u16* Vbp = Wb + 2048 + (t & 1)*1024;
        const bf16x8 kc0 = *(const bf16x8*)(Kb + kOff0);
        const bf16x8 kc1 = *(const bf16x8*)(Kb + kOff1);
        bf16x4 va[4];
        #pragma unroll
        for (int dt = 0; dt < 4; ++dt)
            va[dt] = *(const bf16x4*)(Vbp + dt*256 + vroff);
        // ---- S^T[strip kv][64 q], Q fragments from LDS ----
        f32x4 s[4];
        #pragma unroll
        for (int sub = 0; sub < 4; ++sub) {
            const int qrow = sub*16 + c16;
            const bf16x8 qb0 = *(const bf16x8*)(Qs + qrow*64 + ((g ^ (c16&7))*8));
            const bf16x8 qb1 = *(const bf16x8*)(Qs + qrow*64 + (((4+g) ^ (c16&7))*8));
            f32x4 sv = __builtin_amdgcn_mfma_f32_16x16x32_bf16(kc0, qb0, fz, 0, 0, 0);
            s[sub]   = __builtin_amdgcn_mfma_f32_16x16x32_bf16(kc1, qb1, sv, 0, 0, 0);
        }
        // ---- softmax numerator (exp2, static max 0), in-register P^T ----
        bf16x4 pt[4];
        if (t < qt) {
            #pragma unroll
            for (int sub = 0; sub < 4; ++sub) {
                float p0 = fexp2(s[sub][0]), p1 = fexp2(s[sub][1]);
                float p2 = fexp2(s[sub][2]), p3 = fexp2(s[sub][3]);
                lsum[sub] += (p0 + p1) + (p2 + p3);
                bf16x4 pv;
                pv[0] = (__bf16)p0; pv[1] = (__bf16)p1;
                pv[2] = (__bf16)p2; pv[3] = (__bf16)p3;
                pt[sub] = pv;
            }
        } else {  // diagonal tile: causal mask
            const int kvbase = t*64 + 16*w + 4*g;
            #pragma unroll
            for (int sub = 0; sub < 4; ++sub) {
                const int qi = Q0 + sub*16 + c16;
                bf16x4 pv; float a = 0.f;
                #pragma unroll
                for (int r = 0; r < 4; ++r) {
                    float p = (kvbase + r <= qi) ? fexp2(s[sub][r]) : 0.0f;
                    a += p; pv[r] = (__bf16)p;
                }
                lsum[sub] += a; pt[sub] = pv;
            }
        }
        // ---- O^T += V^T . P^T ----
        #pragma unroll
        for (int dt = 0; dt < 4; ++dt)
          #pragma unroll
          for (int sub = 0; sub < 4; ++sub)
            oacc[dt][sub] = mfma16(va[dt], pt[sub], oacc[dt][sub]);
    }

    // ---- l totals (register shuffle reduce) ----
    #pragma unroll
    for (int sub = 0; sub < 4; ++sub) {
        float v = lsum[sub];
        v += __shfl_xor(v, 16);
        v += __shfl_xor(v, 32);
        lsum[sub] = v;
    }

    // drain own tail DMAs before smem is repurposed, then block-sync
    asm volatile("s_waitcnt vmcnt(0)" ::: "memory");
    __syncthreads();
    #pragma unroll
    for (int sub = 0; sub < 4; ++sub)
        if (g == 0) lbuf[w*64 + sub*16 + c16] = lsum[sub];

    // ---- cross-wave O reduce: 4 STATIC rounds; wave dt collects d-slice dt ----
    float* img = (float*)smem;   // 4 regions x 1280 f32: [wave][64q x stride20]
    f32x4 ofin[4];
    float ltot[4];
    #pragma unroll
    for (int dt = 0; dt < 4; ++dt) {
        #pragma unroll
        for (int sub = 0; sub < 4; ++sub)
            *(f32x4*)(img + w*1280 + (sub*16 + c16)*20 + g*4) = oacc[dt][sub];
        __syncthreads();
        if (dt == 0) {
            #pragma unroll
            for (int sub = 0; sub < 4; ++sub) {
                const int qr = sub*16 + c16;
                ltot[sub] = lbuf[qr] + lbuf[64 + qr] + lbuf[128 + qr] + lbuf[192 + qr];
            }
        }
        if (w == dt) {
            #pragma unroll
            for (int sub = 0; sub < 4; ++sub) {
                const int off = (sub*16 + c16)*20 + g*4;
                f32x4 a0 = *(const f32x4*)(img + off);
                f32x4 a1 = *(const f32x4*)(img + 1280 + off);
                f32x4 a2 = *(const f32x4*)(img + 2560 + off);
                f32x4 a3 = *(const f32x4*)(img + 3840 + off);
                ofin[sub] = (a0 + a1) + (a2 + a3);
            }
        }
        __syncthreads();
    }

    // ---- store: wave w owns d in [16w, 16w+16) ----
    const int dbase = 16*w + 4*g;
    if (single) {
        #pragma unroll
        for (int sub = 0; sub < 4; ++sub) {
            const int qrow = sub*16 + c16;
            const float inv = 1.0f / ltot[sub];
            const f32x4 o = ofin[sub];
            u16x4 ov;
            ov[0] = f2b(o[0]*inv); ov[1] = f2b(o[1]*inv);
            ov[2] = f2b(o[2]*inv); ov[3] = f2b(o[3]*inv);
            *(u16x4*)(att + (size_t)(b*4096 + Q0 + qrow)*512 + h*64 + dbase) = ov;
        }
    } else {
        u16* onum = part + (size_t)(bh*160 + i) * 4224;   // 8448 B/slot
        float* lout = (float*)(onum + 4096);
        #pragma unroll
        for (int sub = 0; sub < 4; ++sub) {
            const int qrow = sub*16 + c16;
            const f32x4 o = ofin[sub];
            u16x4 ov;
            ov[0] = f2b(o[0]); ov[1] = f2b(o[1]);
            ov[2] = f2b(o[2]); ov[3] = f2b(o[3]);
            *(u16x4*)(onum + qrow*64 + dbase) = ov;
            if (w == 0 && g == 0) lout[qrow] = ltot[sub];
        }
    }
}

// ---------------- merge 2/3/4 split-kv partials (q-tiles 16..63) --------------
__global__ __launch_bounds__(256) void attn_merge(
    const u16* __restrict__ part, u16* __restrict__ att)
{
    const int qt = 16 + blockIdx.x, bh = blockIdx.y, b = bh >> 3, h = bh & 7;
    int start, n;
    if (qt < 32)      { start = 16 + 2*(qt-16); n = 2; }
    else if (qt < 48) { start = 48 + 3*(qt-32); n = 3; }
    else              { start = 96 + 4*(qt-48); n = 4; }
    const int t = threadIdx.x;
    const int row = t >> 2, c0 = (t & 3) * 16;
    float acc[16];
    #pragma unroll
    for (int j = 0; j < 16; ++j) acc[j] = 0.f;
    float lt = 0.f;
    const u16* p0 = part + (size_t)(bh*160 + start) * 4224;
    for (int ci = 0; ci < n; ++ci) {
        const u16* pc = p0 + (size_t)ci * 4224;
        lt += ((const float*)(pc + 4096))[row];
        u16x8 a = *(const u16x8*)(pc + row*64 + c0);
        u16x8 bq = *(const u16x8*)(pc + row*64 + c0 + 8);
        #pragma unroll
        for (int j = 0; j < 8; ++j) { acc[j] += b2f(a[j]); acc[8+j] += b2f(bq[j]); }
    }
    const float inv = 1.0f / lt;
    u16x8 o1, o2;
    #pragma unroll
    for (int j = 0; j < 8; ++j) { o1[j] = f2b(acc[j]*inv); o2[j] = f2b(acc[8+j]*inv); }
    u16* dst = att + (size_t)(b*4096 + qt*64 + row)*512 + h*64 + c0;
    *(u16x8*)dst = o1;
    *(u16x8*)(dst + 8) = o2;
}

// -------------------------------------------------------------------------------
extern "C" void kernel_launch(void* const* d_in, const int* in_sizes, int n_in,
                              void* d_out, int out_size, void* d_ws, size_t ws_size,
                              hipStream_t stream)
{
    (void)in_sizes; (void)n_in; (void)out_size; (void)ws_size;
    const float* x   = (const float*)d_in[0];
    const float* Wq  = (const float*)d_in[1];
    const float* Wk  = (const float*)d_in[2];
    const float* Wv  = (const float*)d_in[3];
    const float* Wo  = (const float*)d_in[4];
    const float* bo  = (const float*)d_in[5];
    const float* W1  = (const float*)d_in[6];
    const float* b1  = (const float*)d_in[7];
    const float* W2  = (const float*)d_in[8];
    const float* b2  = (const float*)d_in[9];
    const float* g1  = (const float*)d_in[10];
    const float* be1 = (const float*)d_in[11];
    const float* g2  = (const float*)d_in[12];
    const float* be2 = (const float*)d_in[13];

    char* ws = (char*)d_ws;
    u16*   WqkvT = (u16*)(ws + 0);
    u16*   WoT   = (u16*)(ws + 1572864);
    u16*   W1T   = (u16*)(ws + 2097152);
    u16*   W2T   = (u16*)(ws + 4194304);
    u16*   H     = (u16*)(ws + 6291456);    // ln1/ln2 out [8192][512] bf16
    u16*   PART  = (u16*)(ws + 6291456);    // attn partials 160/bh x16 x8448B =21.6MB
                                            // (H dead; consumed by merge before Wo writes X2)
    float* X2    = (float*)(ws + 14680064); // post-attention residual (f32)
    u16*   QKV   = (u16*)(ws + 31457280);   // [8192][1536] (V cols unwritten)
    u16*   VT    = (u16*)(ws + 56623104);   // [1024][4096], from QKV-gemm epilogue
    u16*   ATT   = (u16*)(ws + 65011712);   // [8192][512]
    u16*   F1    = (u16*)(ws + 31457280);   // [8192][2048], reuses QKV+VT

    prep_w<<<3072, 256, 0, stream>>>(Wq, Wk, Wv, Wo, W1, W2,
                                     WqkvT, WoT, W1T, W2T);
    ln_rows<<<2048, 256, 0, stream>>>(x, g1, be1, H);
    gemm_bt<48, 2, 12><<<768, 256, 0, stream>>>(H, WqkvT, 1536, 512,
                                                nullptr, nullptr, QKV, VT);
    attn_fwd<<<dim3(160, 16), 256, 0, stream>>>(QKV, VT, PART, ATT);
    attn_merge<<<dim3(48, 16), 256, 0, stream>>>(PART, ATT);
    gemm_m64<11, 8><<<1024, 256, 0, stream>>>(ATT, WoT, 512, 512,
                                              bo, x, X2);
    ln_rows<<<2048, 256, 0, stream>>>(X2, g2, be2, H);
    gemm_bt<5, 2, 16><<<1024, 256, 0, stream>>>(H, W1T, 2048, 512,
                                                b1, nullptr, F1, nullptr);
    gemm_m64<11, 8><<<1024, 256, 0, stream>>>(F1, W2T, 512, 2048,
                                              b2, X2, (float*)d_out);
}